// Round 7
// baseline (115.902 us; speedup 1.0000x reference)
//
#include <hip/hip_runtime.h>

#define N_NODES 50000
#define N_EDGES 800000
#define D_FEAT  96
#define F8      12                    // 16B ushort8 groups per 192B bf16 row
#define ROWS_PER_BLOCK 32
#define BLOCK (ROWS_PER_BLOCK * F8)   // 384

#define N_CVT  (N_NODES * D_FEAT / 8) // 600000 convert threads (8 floats each)

// d_ws layout (bytes)
#define ROWPTR_OFF 0                      // (N+1)*4 = 200004
#define EMB_OFF    200192                 // bf16 embeds, 9,600,000 B
#define HIST_OFF   9800192                // 64 bins x 128B = 8192
#define CURSOR_OFF 9808384                // 64 bins x 128B = 8192
#define PERM_OFF   9816576                // N*4 = 200000
#define WS_NEEDED  (PERM_OFF + (size_t)N_NODES * 4)

#define NBINS      64
#define BIN_STRIDE 32                     // ints -> 128B per bin (no line sharing)

__device__ inline unsigned int f2bf(float f) {  // RNE f32->bf16 in low 16
    unsigned u = __float_as_uint(f);
    return (u + 0x7fffu + ((u >> 16) & 1u)) >> 16;
}

// Prep: f32->bf16 convert (600K threads) + row_ptr binary search + length
// histogram (LDS-aggregated, padded global bins). No cross-block deps.
__global__ void prep_kernel(const int* __restrict__ rows,
                            const float* __restrict__ embeds,
                            unsigned int* __restrict__ emb_bf,
                            int* __restrict__ row_ptr,
                            int* __restrict__ hist) {
    __shared__ int lbin[NBINS];
    const int t = threadIdx.x;
    if (t < NBINS) lbin[t] = 0;
    __syncthreads();

    const int idx = blockIdx.x * blockDim.x + t;
    if (idx < N_CVT) {
        const float4* src = (const float4*)embeds;
        float4 a = src[idx * 2 + 0];
        float4 b = src[idx * 2 + 1];
        uint4 p;
        p.x = f2bf(a.x) | (f2bf(a.y) << 16);
        p.y = f2bf(a.z) | (f2bf(a.w) << 16);
        p.z = f2bf(b.x) | (f2bf(b.y) << 16);
        p.w = f2bf(b.z) | (f2bf(b.w) << 16);
        ((uint4*)emb_bf)[idx] = p;
    }
    if (idx <= N_NODES) {
        int lo = 0, hi = N_EDGES;
        while (lo < hi) {
            int mid = (lo + hi) >> 1;
            if (rows[mid] < idx) lo = mid + 1;
            else hi = mid;
        }
        row_ptr[idx] = lo;
        if (idx < N_NODES) {
            int lo2 = lo, hi2 = N_EDGES;          // lower_bound(idx+1) >= lo
            int tgt = idx + 1;
            while (lo2 < hi2) {
                int mid = (lo2 + hi2) >> 1;
                if (rows[mid] < tgt) lo2 = mid + 1;
                else hi2 = mid;
            }
            int len = lo2 - lo;
            int b = len < (NBINS - 1) ? len : (NBINS - 1);
            atomicAdd(&lbin[b], 1);
        }
    }
    __syncthreads();
    if (t < NBINS && lbin[t]) atomicAdd(&hist[t * BIN_STRIDE], lbin[t]);
}

// Scatter: counting-sort rows by length into perm. Order within a bin is
// race-determined but output values are order-independent -> deterministic.
__global__ void scatter_kernel(const int* __restrict__ row_ptr,
                               const int* __restrict__ hist,
                               int* __restrict__ cursor,
                               int* __restrict__ perm) {
    __shared__ int prefix[NBINS];
    const int t = threadIdx.x;
    if (t < NBINS) prefix[t] = hist[t * BIN_STRIDE];
    __syncthreads();
    if (t == 0) {
        int acc = 0;
        for (int i = 0; i < NBINS; ++i) { int v = prefix[i]; prefix[i] = acc; acc += v; }
    }
    __syncthreads();
    const int r = blockIdx.x * blockDim.x + t;
    if (r < N_NODES) {
        int len = row_ptr[r + 1] - row_ptr[r];
        int b = len < (NBINS - 1) ? len : (NBINS - 1);
        int rank = atomicAdd(&cursor[b * BIN_STRIDE], 1);
        perm[prefix[b] + rank] = r;
    }
}

// Unpack uint4 (8 bf16) and fmac into two float4 accumulators.
#define ACCUM(mm, vv, A, B) {                                   \
    float f0 = __uint_as_float((mm).x << 16);                   \
    float f1 = __uint_as_float((mm).x & 0xffff0000u);           \
    float f2 = __uint_as_float((mm).y << 16);                   \
    float f3 = __uint_as_float((mm).y & 0xffff0000u);           \
    float f4 = __uint_as_float((mm).z << 16);                   \
    float f5 = __uint_as_float((mm).z & 0xffff0000u);           \
    float f6 = __uint_as_float((mm).w << 16);                   \
    float f7 = __uint_as_float((mm).w & 0xffff0000u);           \
    A.x += (vv) * f0; A.y += (vv) * f1; A.z += (vv) * f2; A.w += (vv) * f3; \
    B.x += (vv) * f4; B.y += (vv) * f5; B.z += (vv) * f6; B.w += (vv) * f7; }

// SpMM over bf16 embeds, rows taken through the length-sorted permutation:
// all rows in a wave have identical length -> lockstep loops, uniform tails.
__global__ __launch_bounds__(BLOCK, 2) void spmm_bf16_kernel(
    const int*          __restrict__ cols,
    const float*        __restrict__ vals,
    const unsigned int* __restrict__ emb_bf,
    const int*          __restrict__ row_ptr,
    const int*          __restrict__ perm,
    float*              __restrict__ out) {
    const int tid       = threadIdx.x;
    const int local_row = tid / F8;               // 0..31
    const int fg        = tid - local_row * F8;   // 0..11
    const int rv        = blockIdx.x * ROWS_PER_BLOCK + local_row;
    if (rv >= N_NODES) return;
    const int r = perm[rv];

    const uint4* __restrict__ emb = (const uint4*)emb_bf;

    int e   = row_ptr[r];
    int end = row_ptr[r + 1];

    float4 accA0 = make_float4(0.f, 0.f, 0.f, 0.f);
    float4 accB0 = accA0, accA1 = accA0, accB1 = accA0;

    for (; e + 7 < end; e += 8) {
        int c0 = cols[e + 0], c1 = cols[e + 1], c2 = cols[e + 2], c3 = cols[e + 3];
        int c4 = cols[e + 4], c5 = cols[e + 5], c6 = cols[e + 6], c7 = cols[e + 7];
        float v0 = vals[e + 0], v1 = vals[e + 1], v2 = vals[e + 2], v3 = vals[e + 3];
        float v4 = vals[e + 4], v5 = vals[e + 5], v6 = vals[e + 6], v7 = vals[e + 7];

        uint4 m0 = emb[(size_t)c0 * F8 + fg];
        uint4 m1 = emb[(size_t)c1 * F8 + fg];
        uint4 m2 = emb[(size_t)c2 * F8 + fg];
        uint4 m3 = emb[(size_t)c3 * F8 + fg];
        uint4 m4 = emb[(size_t)c4 * F8 + fg];
        uint4 m5 = emb[(size_t)c5 * F8 + fg];
        uint4 m6 = emb[(size_t)c6 * F8 + fg];
        uint4 m7 = emb[(size_t)c7 * F8 + fg];

        ACCUM(m0, v0, accA0, accB0);
        ACCUM(m1, v1, accA1, accB1);
        ACCUM(m2, v2, accA0, accB0);
        ACCUM(m3, v3, accA1, accB1);
        ACCUM(m4, v4, accA0, accB0);
        ACCUM(m5, v5, accA1, accB1);
        ACCUM(m6, v6, accA0, accB0);
        ACCUM(m7, v7, accA1, accB1);
    }
    if (e + 3 < end) {
        int c0 = cols[e + 0], c1 = cols[e + 1], c2 = cols[e + 2], c3 = cols[e + 3];
        float v0 = vals[e + 0], v1 = vals[e + 1], v2 = vals[e + 2], v3 = vals[e + 3];
        uint4 m0 = emb[(size_t)c0 * F8 + fg];
        uint4 m1 = emb[(size_t)c1 * F8 + fg];
        uint4 m2 = emb[(size_t)c2 * F8 + fg];
        uint4 m3 = emb[(size_t)c3 * F8 + fg];
        ACCUM(m0, v0, accA0, accB0);
        ACCUM(m1, v1, accA1, accB1);
        ACCUM(m2, v2, accA0, accB0);
        ACCUM(m3, v3, accA1, accB1);
        e += 4;
    }
    for (; e < end; ++e) {
        int   c = cols[e];
        float v = vals[e];
        uint4 m = emb[(size_t)c * F8 + fg];
        ACCUM(m, v, accA0, accB0);
    }

    float4 sA, sB;
    sA.x = accA0.x + accA1.x; sA.y = accA0.y + accA1.y;
    sA.z = accA0.z + accA1.z; sA.w = accA0.w + accA1.w;
    sB.x = accB0.x + accB1.x; sB.y = accB0.y + accB1.y;
    sB.z = accB0.z + accB1.z; sB.w = accB0.w + accB1.w;
    float4* o = (float4*)out;
    o[(size_t)r * 24 + fg * 2 + 0] = sA;
    o[(size_t)r * 24 + fg * 2 + 1] = sB;
}

// ---------- fallback f32 path (proven round-2/5 structure) ----------
#define F4 (D_FEAT / 4)
__global__ __launch_bounds__(384, 2) void spmm_f32_kernel(
    const int*   __restrict__ cols,
    const float* __restrict__ vals,
    const float* __restrict__ embeds,
    const int*   __restrict__ row_ptr,
    float*       __restrict__ out) {
    const int tid       = threadIdx.x;
    const int local_row = tid / F4;
    const int fg        = tid - local_row * F4;
    const int r         = blockIdx.x * 16 + local_row;
    if (r >= N_NODES) return;
    const float4* __restrict__ emb4 = (const float4*)embeds;
    int e = row_ptr[r], end = row_ptr[r + 1];
    float4 a0 = make_float4(0.f, 0.f, 0.f, 0.f), a1 = a0, a2 = a0, a3 = a0;
    for (; e + 3 < end; e += 4) {
        int c0 = cols[e], c1 = cols[e + 1], c2 = cols[e + 2], c3 = cols[e + 3];
        float v0 = vals[e], v1 = vals[e + 1], v2 = vals[e + 2], v3 = vals[e + 3];
        float4 m0 = emb4[c0 * F4 + fg], m1 = emb4[c1 * F4 + fg];
        float4 m2 = emb4[c2 * F4 + fg], m3 = emb4[c3 * F4 + fg];
        a0.x += v0 * m0.x; a0.y += v0 * m0.y; a0.z += v0 * m0.z; a0.w += v0 * m0.w;
        a1.x += v1 * m1.x; a1.y += v1 * m1.y; a1.z += v1 * m1.z; a1.w += v1 * m1.w;
        a2.x += v2 * m2.x; a2.y += v2 * m2.y; a2.z += v2 * m2.z; a2.w += v2 * m2.w;
        a3.x += v3 * m3.x; a3.y += v3 * m3.y; a3.z += v3 * m3.z; a3.w += v3 * m3.w;
    }
    for (; e < end; ++e) {
        int c = cols[e]; float v = vals[e];
        float4 m = emb4[c * F4 + fg];
        a0.x += v * m.x; a0.y += v * m.y; a0.z += v * m.z; a0.w += v * m.w;
    }
    float4 s;
    s.x = (a0.x + a1.x) + (a2.x + a3.x);
    s.y = (a0.y + a1.y) + (a2.y + a3.y);
    s.z = (a0.z + a1.z) + (a2.z + a3.z);
    s.w = (a0.w + a1.w) + (a2.w + a3.w);
    ((float4*)out)[r * F4 + fg] = s;
}

__global__ void build_row_ptr_kernel(const int* __restrict__ rows,
                                     int* __restrict__ row_ptr) {
    int r = blockIdx.x * blockDim.x + threadIdx.x;
    if (r > N_NODES) return;
    int lo = 0, hi = N_EDGES;
    while (lo < hi) {
        int mid = (lo + hi) >> 1;
        if (rows[mid] < r) lo = mid + 1;
        else hi = mid;
    }
    row_ptr[r] = lo;
}

extern "C" void kernel_launch(void* const* d_in, const int* in_sizes, int n_in,
                              void* d_out, int out_size, void* d_ws, size_t ws_size,
                              hipStream_t stream) {
    const int*   rows   = (const int*)  d_in[0];
    const int*   cols   = (const int*)  d_in[1];
    const float* vals   = (const float*)d_in[2];
    const float* embeds = (const float*)d_in[3];
    float*       out    = (float*)      d_out;

    int* row_ptr = (int*)d_ws;

    if (ws_size >= WS_NEEDED) {
        unsigned int* emb_bf = (unsigned int*)((char*)d_ws + EMB_OFF);
        int* hist   = (int*)((char*)d_ws + HIST_OFF);
        int* cursor = (int*)((char*)d_ws + CURSOR_OFF);
        int* perm   = (int*)((char*)d_ws + PERM_OFF);

        // zero hist + cursor (contiguous 16 KB)
        hipMemsetAsync((char*)d_ws + HIST_OFF, 0, 2 * NBINS * BIN_STRIDE * 4,
                       stream);
        {
            int threads = 256;
            int blocks  = (N_CVT + threads - 1) / threads;   // 2344
            prep_kernel<<<blocks, threads, 0, stream>>>(rows, embeds, emb_bf,
                                                        row_ptr, hist);
        }
        {
            int threads = 256;
            int blocks  = (N_NODES + threads - 1) / threads; // 196
            scatter_kernel<<<blocks, threads, 0, stream>>>(row_ptr, hist,
                                                           cursor, perm);
        }
        {
            int blocks = (N_NODES + ROWS_PER_BLOCK - 1) / ROWS_PER_BLOCK; // 1563
            spmm_bf16_kernel<<<blocks, BLOCK, 0, stream>>>(cols, vals, emb_bf,
                                                           row_ptr, perm, out);
        }
    } else {
        {
            int threads = 256;
            int blocks  = (N_NODES + 1 + threads - 1) / threads;
            build_row_ptr_kernel<<<blocks, threads, 0, stream>>>(rows, row_ptr);
        }
        {
            int blocks = (N_NODES + 15) / 16;
            spmm_f32_kernel<<<blocks, 384, 0, stream>>>(cols, vals, embeds,
                                                        row_ptr, out);
        }
    }
}

// Round 8
// 64.419 us; speedup vs baseline: 1.7992x; 1.7992x over previous
//
#include <hip/hip_runtime.h>

#define N_NODES 50000
#define N_EDGES 800000
#define D_FEAT  96
#define ROW_BYTES 192                 // bf16 row = 96*2 B = 12 x 16B granules
#define ROWS_PER_BLOCK 32
#define SPMM_BLOCK 128                // 2 waves; 4 lanes/row, 16 rows/wave

#define N_CVT  (N_NODES * D_FEAT / 8) // 600000 convert threads (8 floats each)

// d_ws layout (bytes)
#define ROWPTR_OFF 0                      // (N+1)*4 = 200004
#define EMB_OFF    200192                 // bf16 embeds, 9,600,000 B (16B aligned)
#define HIST_OFF   9800192                // 64 bins x 128B = 8192
#define CURSOR_OFF 9808384                // 64 bins x 128B = 8192
#define PERM_OFF   9816576                // N*4 = 200000
#define WS_NEEDED  (PERM_OFF + (size_t)N_NODES * 4)

#define NBINS      64
#define BIN_STRIDE 32                     // ints -> 128B per bin

typedef unsigned int u32x4 __attribute__((ext_vector_type(4)));
typedef float        f32x4 __attribute__((ext_vector_type(4)));

__device__ inline unsigned int f2bf(float f) {  // RNE f32->bf16 in low 16
    unsigned u = __float_as_uint(f);
    return (u + 0x7fffu + ((u >> 16) & 1u)) >> 16;
}

// 16B global load via inline asm: issued exactly where written, results
// forced co-resident in VGPRs (compiler cannot split the batch).
__device__ __forceinline__ u32x4 gload16(const void* p) {
    u32x4 r;
    asm volatile("global_load_dwordx4 %0, %1, off" : "=v"(r) : "v"(p));
    return r;
}

// Prep: f32->bf16 convert + row_ptr binary search + length histogram.
__global__ void prep_kernel(const int* __restrict__ rows,
                            const float* __restrict__ embeds,
                            unsigned int* __restrict__ emb_bf,
                            int* __restrict__ row_ptr,
                            int* __restrict__ hist) {
    __shared__ int lbin[NBINS];
    const int t = threadIdx.x;
    if (t < NBINS) lbin[t] = 0;
    __syncthreads();

    const int idx = blockIdx.x * blockDim.x + t;
    if (idx < N_CVT) {
        const float4* src = (const float4*)embeds;
        float4 a = src[idx * 2 + 0];
        float4 b = src[idx * 2 + 1];
        uint4 p;
        p.x = f2bf(a.x) | (f2bf(a.y) << 16);
        p.y = f2bf(a.z) | (f2bf(a.w) << 16);
        p.z = f2bf(b.x) | (f2bf(b.y) << 16);
        p.w = f2bf(b.z) | (f2bf(b.w) << 16);
        ((uint4*)emb_bf)[idx] = p;
    }
    if (idx <= N_NODES) {
        int lo = 0, hi = N_EDGES;
        while (lo < hi) {
            int mid = (lo + hi) >> 1;
            if (rows[mid] < idx) lo = mid + 1;
            else hi = mid;
        }
        row_ptr[idx] = lo;
        if (idx < N_NODES) {
            int lo2 = lo, hi2 = N_EDGES;
            int tgt = idx + 1;
            while (lo2 < hi2) {
                int mid = (lo2 + hi2) >> 1;
                if (rows[mid] < tgt) lo2 = mid + 1;
                else hi2 = mid;
            }
            int len = lo2 - lo;
            int b = len < (NBINS - 1) ? len : (NBINS - 1);
            atomicAdd(&lbin[b], 1);
        }
    }
    __syncthreads();
    if (t < NBINS && lbin[t]) atomicAdd(&hist[t * BIN_STRIDE], lbin[t]);
}

// Scatter v2 (two-level): block LDS histogram -> ONE global atomic per
// (block,bin) for the inter-block base -> LDS atomics for within-block rank.
// Round 7's 50K same-address global atomics (60us) -> ~12K spread atomics.
// perm filled DESCENDING by length so long-row blocks dispatch first.
__global__ void scatter_kernel(const int* __restrict__ row_ptr,
                               const int* __restrict__ hist,
                               int* __restrict__ cursor,
                               int* __restrict__ perm) {
    __shared__ int prefix[NBINS];
    __shared__ int lhist[NBINS];
    __shared__ int lbase[NBINS];
    __shared__ int lcur[NBINS];
    const int t = threadIdx.x;
    if (t < NBINS) { lhist[t] = 0; lcur[t] = 0; prefix[t] = hist[t * BIN_STRIDE]; }
    __syncthreads();

    const int r = blockIdx.x * blockDim.x + t;
    int b = -1;
    if (r < N_NODES) {
        int len = row_ptr[r + 1] - row_ptr[r];
        b = len < (NBINS - 1) ? len : (NBINS - 1);
        atomicAdd(&lhist[b], 1);
    }
    if (t == 0) {  // exclusive scan of 64 bins (runs alongside LDS atomics)
        int acc = 0;
        for (int i = 0; i < NBINS; ++i) { int v = prefix[i]; prefix[i] = acc; acc += v; }
    }
    __syncthreads();
    if (t < NBINS && lhist[t]) lbase[t] = atomicAdd(&cursor[t * BIN_STRIDE], lhist[t]);
    __syncthreads();
    if (r < N_NODES) {
        int rank = atomicAdd(&lcur[b], 1);
        int pos  = prefix[b] + lbase[b] + rank;      // ascending-length position
        perm[N_NODES - 1 - pos] = r;                  // store descending
    }
}

// Unpack 8 bf16 (u32x4) scaled by v into two f32x4 accumulators.
#define ACC(m, vv, A, B) do {                                   \
    A[0] += (vv) * __uint_as_float((m)[0] << 16);               \
    A[1] += (vv) * __uint_as_float((m)[0] & 0xffff0000u);       \
    A[2] += (vv) * __uint_as_float((m)[1] << 16);               \
    A[3] += (vv) * __uint_as_float((m)[1] & 0xffff0000u);       \
    B[0] += (vv) * __uint_as_float((m)[2] << 16);               \
    B[1] += (vv) * __uint_as_float((m)[2] & 0xffff0000u);       \
    B[2] += (vv) * __uint_as_float((m)[3] << 16);               \
    B[3] += (vv) * __uint_as_float((m)[3] & 0xffff0000u);       \
} while (0)

// SpMM: 4 lanes/row, 3 granules (48B) per lane, 4-edge unroll ->
// 12 asm gathers in flight per lane before a single vmcnt(0).
// Rows via length-sorted perm -> equal trip counts across a wave.
__global__ __launch_bounds__(SPMM_BLOCK, 2) void spmm_kernel(
    const int*          __restrict__ cols,
    const float*        __restrict__ vals,
    const unsigned int* __restrict__ emb_bf,
    const int*          __restrict__ row_ptr,
    const int*          __restrict__ perm,
    float*              __restrict__ out) {
    const int tid  = threadIdx.x;
    const int lrow = tid >> 2;            // 0..31 (16 rows per wave)
    const int lane = tid & 3;             // 0..3
    const int rv   = blockIdx.x * ROWS_PER_BLOCK + lrow;
    if (rv >= N_NODES) return;
    const int r = perm[rv];

    const char* embB = (const char*)emb_bf;
    int e   = row_ptr[r];
    int end = row_ptr[r + 1];

    f32x4 aA0 = {0.f,0.f,0.f,0.f}, aB0 = aA0;
    f32x4 aA1 = aA0, aB1 = aA0, aA2 = aA0, aB2 = aA0;

    const int laneoff = lane * 16;

    for (; e + 3 < end; e += 4) {
        int c0 = cols[e + 0], c1 = cols[e + 1], c2 = cols[e + 2], c3 = cols[e + 3];
        float v0 = vals[e + 0], v1 = vals[e + 1], v2 = vals[e + 2], v3 = vals[e + 3];
        const char* b0 = embB + (size_t)c0 * ROW_BYTES + laneoff;
        const char* b1 = embB + (size_t)c1 * ROW_BYTES + laneoff;
        const char* b2 = embB + (size_t)c2 * ROW_BYTES + laneoff;
        const char* b3 = embB + (size_t)c3 * ROW_BYTES + laneoff;

        u32x4 m00 = gload16(b0);       u32x4 m01 = gload16(b0 + 64);
        u32x4 m02 = gload16(b0 + 128);
        u32x4 m10 = gload16(b1);       u32x4 m11 = gload16(b1 + 64);
        u32x4 m12 = gload16(b1 + 128);
        u32x4 m20 = gload16(b2);       u32x4 m21 = gload16(b2 + 64);
        u32x4 m22 = gload16(b2 + 128);
        u32x4 m30 = gload16(b3);       u32x4 m31 = gload16(b3 + 64);
        u32x4 m32 = gload16(b3 + 128);

        asm volatile("s_waitcnt vmcnt(0)" ::: "memory");
        __builtin_amdgcn_sched_barrier(0);

        ACC(m00, v0, aA0, aB0); ACC(m01, v0, aA1, aB1); ACC(m02, v0, aA2, aB2);
        ACC(m10, v1, aA0, aB0); ACC(m11, v1, aA1, aB1); ACC(m12, v1, aA2, aB2);
        ACC(m20, v2, aA0, aB0); ACC(m21, v2, aA1, aB1); ACC(m22, v2, aA2, aB2);
        ACC(m30, v3, aA0, aB0); ACC(m31, v3, aA1, aB1); ACC(m32, v3, aA2, aB2);
    }
    for (; e < end; ++e) {
        int   c = cols[e];
        float v = vals[e];
        const char* b = embB + (size_t)c * ROW_BYTES + laneoff;
        u32x4 m0 = gload16(b);
        u32x4 m1 = gload16(b + 64);
        u32x4 m2 = gload16(b + 128);
        asm volatile("s_waitcnt vmcnt(0)" ::: "memory");
        __builtin_amdgcn_sched_barrier(0);
        ACC(m0, v, aA0, aB0); ACC(m1, v, aA1, aB1); ACC(m2, v, aA2, aB2);
    }

    // lane owns granules {lane, lane+4, lane+8}; granule g = feats [8g, 8g+8)
    f32x4* o = (f32x4*)out;
    const size_t ob = (size_t)r * 24;
    o[ob + (lane + 0) * 2 + 0] = aA0;  o[ob + (lane + 0) * 2 + 1] = aB0;
    o[ob + (lane + 4) * 2 + 0] = aA1;  o[ob + (lane + 4) * 2 + 1] = aB1;
    o[ob + (lane + 8) * 2 + 0] = aA2;  o[ob + (lane + 8) * 2 + 1] = aB2;
}

// ---------- fallback f32 path (proven round-2/5 structure) ----------
#define F4 (D_FEAT / 4)
__global__ __launch_bounds__(384, 2) void spmm_f32_kernel(
    const int*   __restrict__ cols,
    const float* __restrict__ vals,
    const float* __restrict__ embeds,
    const int*   __restrict__ row_ptr,
    float*       __restrict__ out) {
    const int tid       = threadIdx.x;
    const int local_row = tid / F4;
    const int fg        = tid - local_row * F4;
    const int r         = blockIdx.x * 16 + local_row;
    if (r >= N_NODES) return;
    const float4* __restrict__ emb4 = (const float4*)embeds;
    int e = row_ptr[r], end = row_ptr[r + 1];
    float4 a0 = make_float4(0.f, 0.f, 0.f, 0.f), a1 = a0, a2 = a0, a3 = a0;
    for (; e + 3 < end; e += 4) {
        int c0 = cols[e], c1 = cols[e + 1], c2 = cols[e + 2], c3 = cols[e + 3];
        float v0 = vals[e], v1 = vals[e + 1], v2 = vals[e + 2], v3 = vals[e + 3];
        float4 m0 = emb4[c0 * F4 + fg], m1 = emb4[c1 * F4 + fg];
        float4 m2 = emb4[c2 * F4 + fg], m3 = emb4[c3 * F4 + fg];
        a0.x += v0 * m0.x; a0.y += v0 * m0.y; a0.z += v0 * m0.z; a0.w += v0 * m0.w;
        a1.x += v1 * m1.x; a1.y += v1 * m1.y; a1.z += v1 * m1.z; a1.w += v1 * m1.w;
        a2.x += v2 * m2.x; a2.y += v2 * m2.y; a2.z += v2 * m2.z; a2.w += v2 * m2.w;
        a3.x += v3 * m3.x; a3.y += v3 * m3.y; a3.z += v3 * m3.z; a3.w += v3 * m3.w;
    }
    for (; e < end; ++e) {
        int c = cols[e]; float v = vals[e];
        float4 m = emb4[c * F4 + fg];
        a0.x += v * m.x; a0.y += v * m.y; a0.z += v * m.z; a0.w += v * m.w;
    }
    float4 s;
    s.x = (a0.x + a1.x) + (a2.x + a3.x);
    s.y = (a0.y + a1.y) + (a2.y + a3.y);
    s.z = (a0.z + a1.z) + (a2.z + a3.z);
    s.w = (a0.w + a1.w) + (a2.w + a3.w);
    ((float4*)out)[r * F4 + fg] = s;
}

__global__ void build_row_ptr_kernel(const int* __restrict__ rows,
                                     int* __restrict__ row_ptr) {
    int r = blockIdx.x * blockDim.x + threadIdx.x;
    if (r > N_NODES) return;
    int lo = 0, hi = N_EDGES;
    while (lo < hi) {
        int mid = (lo + hi) >> 1;
        if (rows[mid] < r) lo = mid + 1;
        else hi = mid;
    }
    row_ptr[r] = lo;
}

extern "C" void kernel_launch(void* const* d_in, const int* in_sizes, int n_in,
                              void* d_out, int out_size, void* d_ws, size_t ws_size,
                              hipStream_t stream) {
    const int*   rows   = (const int*)  d_in[0];
    const int*   cols   = (const int*)  d_in[1];
    const float* vals   = (const float*)d_in[2];
    const float* embeds = (const float*)d_in[3];
    float*       out    = (float*)      d_out;

    int* row_ptr = (int*)d_ws;

    if (ws_size >= WS_NEEDED) {
        unsigned int* emb_bf = (unsigned int*)((char*)d_ws + EMB_OFF);
        int* hist   = (int*)((char*)d_ws + HIST_OFF);
        int* cursor = (int*)((char*)d_ws + CURSOR_OFF);
        int* perm   = (int*)((char*)d_ws + PERM_OFF);

        hipMemsetAsync((char*)d_ws + HIST_OFF, 0, 2 * NBINS * BIN_STRIDE * 4,
                       stream);
        {
            int threads = 256;
            int blocks  = (N_CVT + threads - 1) / threads;   // 2344
            prep_kernel<<<blocks, threads, 0, stream>>>(rows, embeds, emb_bf,
                                                        row_ptr, hist);
        }
        {
            int threads = 256;
            int blocks  = (N_NODES + threads - 1) / threads; // 196
            scatter_kernel<<<blocks, threads, 0, stream>>>(row_ptr, hist,
                                                           cursor, perm);
        }
        {
            int blocks = (N_NODES + ROWS_PER_BLOCK - 1) / ROWS_PER_BLOCK; // 1563
            spmm_kernel<<<blocks, SPMM_BLOCK, 0, stream>>>(cols, vals, emb_bf,
                                                           row_ptr, perm, out);
        }
    } else {
        {
            int threads = 256;
            int blocks  = (N_NODES + 1 + threads - 1) / threads;
            build_row_ptr_kernel<<<blocks, threads, 0, stream>>>(rows, row_ptr);
        }
        {
            int blocks = (N_NODES + 15) / 16;
            spmm_f32_kernel<<<blocks, 384, 0, stream>>>(cols, vals, embeds,
                                                        row_ptr, out);
        }
    }
}

// Round 9
// 58.524 us; speedup vs baseline: 1.9804x; 1.1007x over previous
//
#include <hip/hip_runtime.h>

#define N_NODES 50000
#define N_EDGES 800000
#define D_FEAT  96
#define F8      12                    // 16B ushort8 granules per 192B bf16 row
#define ROWS_PER_BLOCK 32
#define BLOCK (ROWS_PER_BLOCK * F8)   // 384

#define N_CVT  (N_NODES * D_FEAT / 8) // 600000 convert threads (8 floats each)

// d_ws layout (bytes)
#define ROWPTR_OFF 0                      // (N+1)*4 = 200004
#define EMB_OFF    200192                 // bf16 embeds, 9,600,000 B
#define HIST_OFF   9800192                // 64 bins x 128B = 8192
#define CURSOR_OFF 9808384                // 64 bins x 128B = 8192
#define PERM_OFF   9816576                // N*4 = 200000
#define WS_NEEDED  (PERM_OFF + (size_t)N_NODES * 4)

#define NBINS      64
#define BIN_STRIDE 32                     // ints -> 128B per bin

__device__ inline unsigned int f2bf(float f) {  // RNE f32->bf16 in low 16
    unsigned u = __float_as_uint(f);
    return (u + 0x7fffu + ((u >> 16) & 1u)) >> 16;
}

// Prep: f32->bf16 convert + row_ptr binary search + length histogram.
__global__ void prep_kernel(const int* __restrict__ rows,
                            const float* __restrict__ embeds,
                            unsigned int* __restrict__ emb_bf,
                            int* __restrict__ row_ptr,
                            int* __restrict__ hist) {
    __shared__ int lbin[NBINS];
    const int t = threadIdx.x;
    if (t < NBINS) lbin[t] = 0;
    __syncthreads();

    const int idx = blockIdx.x * blockDim.x + t;
    if (idx < N_CVT) {
        const float4* src = (const float4*)embeds;
        float4 a = src[idx * 2 + 0];
        float4 b = src[idx * 2 + 1];
        uint4 p;
        p.x = f2bf(a.x) | (f2bf(a.y) << 16);
        p.y = f2bf(a.z) | (f2bf(a.w) << 16);
        p.z = f2bf(b.x) | (f2bf(b.y) << 16);
        p.w = f2bf(b.z) | (f2bf(b.w) << 16);
        ((uint4*)emb_bf)[idx] = p;
    }
    if (idx <= N_NODES) {
        int lo = 0, hi = N_EDGES;
        while (lo < hi) {
            int mid = (lo + hi) >> 1;
            if (rows[mid] < idx) lo = mid + 1;
            else hi = mid;
        }
        row_ptr[idx] = lo;
        if (idx < N_NODES) {
            int lo2 = lo, hi2 = N_EDGES;
            int tgt = idx + 1;
            while (lo2 < hi2) {
                int mid = (lo2 + hi2) >> 1;
                if (rows[mid] < tgt) lo2 = mid + 1;
                else hi2 = mid;
            }
            int len = lo2 - lo;
            int b = len < (NBINS - 1) ? len : (NBINS - 1);
            atomicAdd(&lbin[b], 1);
        }
    }
    __syncthreads();
    if (t < NBINS && lbin[t]) atomicAdd(&hist[t * BIN_STRIDE], lbin[t]);
}

// Two-level counting-sort scatter (proven round 8: ~3us, was 60us with
// naive same-address atomics). perm filled DESCENDING by length.
__global__ void scatter_kernel(const int* __restrict__ row_ptr,
                               const int* __restrict__ hist,
                               int* __restrict__ cursor,
                               int* __restrict__ perm) {
    __shared__ int prefix[NBINS];
    __shared__ int lhist[NBINS];
    __shared__ int lbase[NBINS];
    __shared__ int lcur[NBINS];
    const int t = threadIdx.x;
    if (t < NBINS) { lhist[t] = 0; lcur[t] = 0; prefix[t] = hist[t * BIN_STRIDE]; }
    __syncthreads();

    const int r = blockIdx.x * blockDim.x + t;
    int b = -1;
    if (r < N_NODES) {
        int len = row_ptr[r + 1] - row_ptr[r];
        b = len < (NBINS - 1) ? len : (NBINS - 1);
        atomicAdd(&lhist[b], 1);
    }
    if (t == 0) {
        int acc = 0;
        for (int i = 0; i < NBINS; ++i) { int v = prefix[i]; prefix[i] = acc; acc += v; }
    }
    __syncthreads();
    if (t < NBINS && lhist[t]) lbase[t] = atomicAdd(&cursor[t * BIN_STRIDE], lhist[t]);
    __syncthreads();
    if (r < N_NODES) {
        int rank = atomicAdd(&lcur[b], 1);
        int pos  = prefix[b] + lbase[b] + rank;
        perm[N_NODES - 1 - pos] = r;          // descending length order
    }
}

// Unpack uint4 (8 bf16) and fmac into two float4 accumulators.
#define ACCUM(mm, vv, A, B) {                                   \
    float f0 = __uint_as_float((mm).x << 16);                   \
    float f1 = __uint_as_float((mm).x & 0xffff0000u);           \
    float f2 = __uint_as_float((mm).y << 16);                   \
    float f3 = __uint_as_float((mm).y & 0xffff0000u);           \
    float f4 = __uint_as_float((mm).z << 16);                   \
    float f5 = __uint_as_float((mm).z & 0xffff0000u);           \
    float f6 = __uint_as_float((mm).w << 16);                   \
    float f7 = __uint_as_float((mm).w & 0xffff0000u);           \
    A.x += (vv) * f0; A.y += (vv) * f1; A.z += (vv) * f2; A.w += (vv) * f3; \
    B.x += (vv) * f4; B.y += (vv) * f5; B.z += (vv) * f6; B.w += (vv) * f7; }

// SpMM over bf16 embeds (round-6 structure: COMPILER-scheduled loads, which
// pipeline across iterations — round 8 proved forced vmcnt(0) batching is
// worse). Rows via length-sorted perm: every row in a wave has identical
// length -> lockstep trip counts, uniform tails, no divergence waste.
__global__ __launch_bounds__(BLOCK, 2) void spmm_bf16_kernel(
    const int*          __restrict__ cols,
    const float*        __restrict__ vals,
    const unsigned int* __restrict__ emb_bf,
    const int*          __restrict__ row_ptr,
    const int*          __restrict__ perm,
    float*              __restrict__ out) {
    const int tid       = threadIdx.x;
    const int local_row = tid / F8;               // 0..31
    const int fg        = tid - local_row * F8;   // 0..11
    const int rv        = blockIdx.x * ROWS_PER_BLOCK + local_row;
    if (rv >= N_NODES) return;
    const int r = perm[rv];

    const uint4* __restrict__ emb = (const uint4*)emb_bf;

    int e   = row_ptr[r];
    int end = row_ptr[r + 1];

    float4 accA0 = make_float4(0.f, 0.f, 0.f, 0.f);
    float4 accB0 = accA0, accA1 = accA0, accB1 = accA0;

    for (; e + 7 < end; e += 8) {
        int c0 = cols[e + 0], c1 = cols[e + 1], c2 = cols[e + 2], c3 = cols[e + 3];
        int c4 = cols[e + 4], c5 = cols[e + 5], c6 = cols[e + 6], c7 = cols[e + 7];
        float v0 = vals[e + 0], v1 = vals[e + 1], v2 = vals[e + 2], v3 = vals[e + 3];
        float v4 = vals[e + 4], v5 = vals[e + 5], v6 = vals[e + 6], v7 = vals[e + 7];

        uint4 m0 = emb[(size_t)c0 * F8 + fg];
        uint4 m1 = emb[(size_t)c1 * F8 + fg];
        uint4 m2 = emb[(size_t)c2 * F8 + fg];
        uint4 m3 = emb[(size_t)c3 * F8 + fg];
        uint4 m4 = emb[(size_t)c4 * F8 + fg];
        uint4 m5 = emb[(size_t)c5 * F8 + fg];
        uint4 m6 = emb[(size_t)c6 * F8 + fg];
        uint4 m7 = emb[(size_t)c7 * F8 + fg];

        ACCUM(m0, v0, accA0, accB0);
        ACCUM(m1, v1, accA1, accB1);
        ACCUM(m2, v2, accA0, accB0);
        ACCUM(m3, v3, accA1, accB1);
        ACCUM(m4, v4, accA0, accB0);
        ACCUM(m5, v5, accA1, accB1);
        ACCUM(m6, v6, accA0, accB0);
        ACCUM(m7, v7, accA1, accB1);
    }
    if (e + 3 < end) {
        int c0 = cols[e + 0], c1 = cols[e + 1], c2 = cols[e + 2], c3 = cols[e + 3];
        float v0 = vals[e + 0], v1 = vals[e + 1], v2 = vals[e + 2], v3 = vals[e + 3];
        uint4 m0 = emb[(size_t)c0 * F8 + fg];
        uint4 m1 = emb[(size_t)c1 * F8 + fg];
        uint4 m2 = emb[(size_t)c2 * F8 + fg];
        uint4 m3 = emb[(size_t)c3 * F8 + fg];
        ACCUM(m0, v0, accA0, accB0);
        ACCUM(m1, v1, accA1, accB1);
        ACCUM(m2, v2, accA0, accB0);
        ACCUM(m3, v3, accA1, accB1);
        e += 4;
    }
    for (; e < end; ++e) {
        int   c = cols[e];
        float v = vals[e];
        uint4 m = emb[(size_t)c * F8 + fg];
        ACCUM(m, v, accA0, accB0);
    }

    float4 sA, sB;
    sA.x = accA0.x + accA1.x; sA.y = accA0.y + accA1.y;
    sA.z = accA0.z + accA1.z; sA.w = accA0.w + accA1.w;
    sB.x = accB0.x + accB1.x; sB.y = accB0.y + accB1.y;
    sB.z = accB0.z + accB1.z; sB.w = accB0.w + accB1.w;
    float4* o = (float4*)out;
    o[(size_t)r * 24 + fg * 2 + 0] = sA;
    o[(size_t)r * 24 + fg * 2 + 1] = sB;
}

// ---------- fallback f32 path (proven round-2/5 structure) ----------
#define F4 (D_FEAT / 4)
__global__ __launch_bounds__(384, 2) void spmm_f32_kernel(
    const int*   __restrict__ cols,
    const float* __restrict__ vals,
    const float* __restrict__ embeds,
    const int*   __restrict__ row_ptr,
    float*       __restrict__ out) {
    const int tid       = threadIdx.x;
    const int local_row = tid / F4;
    const int fg        = tid - local_row * F4;
    const int r         = blockIdx.x * 16 + local_row;
    if (r >= N_NODES) return;
    const float4* __restrict__ emb4 = (const float4*)embeds;
    int e = row_ptr[r], end = row_ptr[r + 1];
    float4 a0 = make_float4(0.f, 0.f, 0.f, 0.f), a1 = a0, a2 = a0, a3 = a0;
    for (; e + 3 < end; e += 4) {
        int c0 = cols[e], c1 = cols[e + 1], c2 = cols[e + 2], c3 = cols[e + 3];
        float v0 = vals[e], v1 = vals[e + 1], v2 = vals[e + 2], v3 = vals[e + 3];
        float4 m0 = emb4[c0 * F4 + fg], m1 = emb4[c1 * F4 + fg];
        float4 m2 = emb4[c2 * F4 + fg], m3 = emb4[c3 * F4 + fg];
        a0.x += v0 * m0.x; a0.y += v0 * m0.y; a0.z += v0 * m0.z; a0.w += v0 * m0.w;
        a1.x += v1 * m1.x; a1.y += v1 * m1.y; a1.z += v1 * m1.z; a1.w += v1 * m1.w;
        a2.x += v2 * m2.x; a2.y += v2 * m2.y; a2.z += v2 * m2.z; a2.w += v2 * m2.w;
        a3.x += v3 * m3.x; a3.y += v3 * m3.y; a3.z += v3 * m3.z; a3.w += v3 * m3.w;
    }
    for (; e < end; ++e) {
        int c = cols[e]; float v = vals[e];
        float4 m = emb4[c * F4 + fg];
        a0.x += v * m.x; a0.y += v * m.y; a0.z += v * m.z; a0.w += v * m.w;
    }
    float4 s;
    s.x = (a0.x + a1.x) + (a2.x + a3.x);
    s.y = (a0.y + a1.y) + (a2.y + a3.y);
    s.z = (a0.z + a1.z) + (a2.z + a3.z);
    s.w = (a0.w + a1.w) + (a2.w + a3.w);
    ((float4*)out)[r * F4 + fg] = s;
}

__global__ void build_row_ptr_kernel(const int* __restrict__ rows,
                                     int* __restrict__ row_ptr) {
    int r = blockIdx.x * blockDim.x + threadIdx.x;
    if (r > N_NODES) return;
    int lo = 0, hi = N_EDGES;
    while (lo < hi) {
        int mid = (lo + hi) >> 1;
        if (rows[mid] < r) lo = mid + 1;
        else hi = mid;
    }
    row_ptr[r] = lo;
}

extern "C" void kernel_launch(void* const* d_in, const int* in_sizes, int n_in,
                              void* d_out, int out_size, void* d_ws, size_t ws_size,
                              hipStream_t stream) {
    const int*   rows   = (const int*)  d_in[0];
    const int*   cols   = (const int*)  d_in[1];
    const float* vals   = (const float*)d_in[2];
    const float* embeds = (const float*)d_in[3];
    float*       out    = (float*)      d_out;

    int* row_ptr = (int*)d_ws;

    if (ws_size >= WS_NEEDED) {
        unsigned int* emb_bf = (unsigned int*)((char*)d_ws + EMB_OFF);
        int* hist   = (int*)((char*)d_ws + HIST_OFF);
        int* cursor = (int*)((char*)d_ws + CURSOR_OFF);
        int* perm   = (int*)((char*)d_ws + PERM_OFF);

        hipMemsetAsync((char*)d_ws + HIST_OFF, 0, 2 * NBINS * BIN_STRIDE * 4,
                       stream);
        {
            int threads = 256;
            int blocks  = (N_CVT + threads - 1) / threads;   // 2344
            prep_kernel<<<blocks, threads, 0, stream>>>(rows, embeds, emb_bf,
                                                        row_ptr, hist);
        }
        {
            int threads = 256;
            int blocks  = (N_NODES + threads - 1) / threads; // 196
            scatter_kernel<<<blocks, threads, 0, stream>>>(row_ptr, hist,
                                                           cursor, perm);
        }
        {
            int blocks = (N_NODES + ROWS_PER_BLOCK - 1) / ROWS_PER_BLOCK; // 1563
            spmm_bf16_kernel<<<blocks, BLOCK, 0, stream>>>(cols, vals, emb_bf,
                                                           row_ptr, perm, out);
        }
    } else {
        {
            int threads = 256;
            int blocks  = (N_NODES + 1 + threads - 1) / threads;
            build_row_ptr_kernel<<<blocks, threads, 0, stream>>>(rows, row_ptr);
        }
        {
            int blocks = (N_NODES + 15) / 16;
            spmm_f32_kernel<<<blocks, 384, 0, stream>>>(cols, vals, embeds,
                                                        row_ptr, out);
        }
    }
}

// Round 11
// 45.927 us; speedup vs baseline: 2.5236x; 1.2743x over previous
//
#include <hip/hip_runtime.h>

#define N_NODES 50000
#define N_EDGES 800000
#define D_FEAT  96
#define ROW_BYTES 192                 // bf16 row: 96*2 B = 12 granules x 16B
#define LPR 12                        // lanes per row (1 granule each)
#define RPB 32                        // rows per block
#define BLOCK (RPB * LPR)             // 384
#define LDS_EDGES 2048                // block edge segment capacity (avg 512)
#define EB 8                          // edges per batch; 2 batches in flight

#define N_CVT  (N_NODES * D_FEAT / 8) // 600000 convert threads
#define EMB_OFF 200192                // after row_ptr (200004 B), 16B-aligned
#define WS_NEEDED (EMB_OFF + (size_t)N_NODES * D_FEAT * 2)

typedef unsigned int u32x4 __attribute__((ext_vector_type(4)));

__device__ __forceinline__ u32x4 gload16(const void* p) {
    u32x4 r;
    asm volatile("global_load_dwordx4 %0, %1, off" : "=v"(r) : "v"(p));
    return r;
}

// wait until <= n vector-memory ops outstanding, then fence the scheduler
// (rule #18: sched_barrier so ALU consumers aren't hoisted above the wait).
#define PIPE_WAIT(n) do {                                              \
    asm volatile("s_waitcnt vmcnt(" #n ")" ::: "memory");              \
    __builtin_amdgcn_sched_barrier(0);                                 \
} while (0)

__device__ __forceinline__ unsigned int f2bf(float f) {  // RNE f32->bf16
    unsigned u = __float_as_uint(f);
    return (u + 0x7fffu + ((u >> 16) & 1u)) >> 16;
}

__device__ __forceinline__ void accum8(u32x4 m, float v, float4& A, float4& B) {
    A.x += v * __uint_as_float(m[0] << 16);
    A.y += v * __uint_as_float(m[0] & 0xffff0000u);
    A.z += v * __uint_as_float(m[1] << 16);
    A.w += v * __uint_as_float(m[1] & 0xffff0000u);
    B.x += v * __uint_as_float(m[2] << 16);
    B.y += v * __uint_as_float(m[2] & 0xffff0000u);
    B.z += v * __uint_as_float(m[3] << 16);
    B.w += v * __uint_as_float(m[3] & 0xffff0000u);
}

// Prep: f32->bf16 convert + row_ptr binary search.
__global__ void prep_kernel(const int* __restrict__ rows,
                            const float* __restrict__ embeds,
                            unsigned int* __restrict__ emb_bf,
                            int* __restrict__ row_ptr) {
    const int idx = blockIdx.x * blockDim.x + threadIdx.x;
    if (idx < N_CVT) {
        const float4* src = (const float4*)embeds;
        float4 a = src[idx * 2 + 0];
        float4 b = src[idx * 2 + 1];
        uint4 p;
        p.x = f2bf(a.x) | (f2bf(a.y) << 16);
        p.y = f2bf(a.z) | (f2bf(a.w) << 16);
        p.z = f2bf(b.x) | (f2bf(b.y) << 16);
        p.w = f2bf(b.z) | (f2bf(b.w) << 16);
        ((uint4*)emb_bf)[idx] = p;
    }
    if (idx <= N_NODES) {
        int lo = 0, hi = N_EDGES;
        while (lo < hi) {
            int mid = (lo + hi) >> 1;
            if (rows[mid] < idx) lo = mid + 1;
            else hi = mid;
        }
        row_ptr[idx] = lo;
    }
}

// issue one batch of 8 gathers (indices clamped to staged range; slots past
// the row's end load harmless real data, later multiplied by v=0)
#define ISSUE(i, M0, M1, M2, M3, M4, M5, M6, M7) do {                  \
    int bx_ = start + (i) * EB;                                        \
    int j0_ = bx_ + 0; j0_ = j0_ > ncl ? ncl : j0_;                    \
    int j1_ = bx_ + 1; j1_ = j1_ > ncl ? ncl : j1_;                    \
    int j2_ = bx_ + 2; j2_ = j2_ > ncl ? ncl : j2_;                    \
    int j3_ = bx_ + 3; j3_ = j3_ > ncl ? ncl : j3_;                    \
    int j4_ = bx_ + 4; j4_ = j4_ > ncl ? ncl : j4_;                    \
    int j5_ = bx_ + 5; j5_ = j5_ > ncl ? ncl : j5_;                    \
    int j6_ = bx_ + 6; j6_ = j6_ > ncl ? ncl : j6_;                    \
    int j7_ = bx_ + 7; j7_ = j7_ > ncl ? ncl : j7_;                    \
    M0 = gload16(embB + (size_t)s_cols[j0_] * ROW_BYTES);              \
    M1 = gload16(embB + (size_t)s_cols[j1_] * ROW_BYTES);              \
    M2 = gload16(embB + (size_t)s_cols[j2_] * ROW_BYTES);              \
    M3 = gload16(embB + (size_t)s_cols[j3_] * ROW_BYTES);              \
    M4 = gload16(embB + (size_t)s_cols[j4_] * ROW_BYTES);              \
    M5 = gload16(embB + (size_t)s_cols[j5_] * ROW_BYTES);              \
    M6 = gload16(embB + (size_t)s_cols[j6_] * ROW_BYTES);              \
    M7 = gload16(embB + (size_t)s_cols[j7_] * ROW_BYTES);              \
} while (0)

#define ACCB(i, M0, M1, M2, M3, M4, M5, M6, M7) do {                   \
    int bx_ = start + (i) * EB;                                        \
    int s0_ = bx_ + 0; float v0_ = s_vals[s0_ > ncl ? ncl : s0_];      \
    int s1_ = bx_ + 1; float v1_ = s_vals[s1_ > ncl ? ncl : s1_];      \
    int s2_ = bx_ + 2; float v2_ = s_vals[s2_ > ncl ? ncl : s2_];      \
    int s3_ = bx_ + 3; float v3_ = s_vals[s3_ > ncl ? ncl : s3_];      \
    int s4_ = bx_ + 4; float v4_ = s_vals[s4_ > ncl ? ncl : s4_];      \
    int s5_ = bx_ + 5; float v5_ = s_vals[s5_ > ncl ? ncl : s5_];      \
    int s6_ = bx_ + 6; float v6_ = s_vals[s6_ > ncl ? ncl : s6_];      \
    int s7_ = bx_ + 7; float v7_ = s_vals[s7_ > ncl ? ncl : s7_];      \
    v0_ = (s0_ < lend) ? v0_ : 0.f;  v1_ = (s1_ < lend) ? v1_ : 0.f;   \
    v2_ = (s2_ < lend) ? v2_ : 0.f;  v3_ = (s3_ < lend) ? v3_ : 0.f;   \
    v4_ = (s4_ < lend) ? v4_ : 0.f;  v5_ = (s5_ < lend) ? v5_ : 0.f;   \
    v6_ = (s6_ < lend) ? v6_ : 0.f;  v7_ = (s7_ < lend) ? v7_ : 0.f;   \
    accum8(M0, v0_, aA, aB); accum8(M1, v1_, aA, aB);                  \
    accum8(M2, v2_, aA, aB); accum8(M3, v3_, aA, aB);                  \
    accum8(M4, v4_, aA, aB); accum8(M5, v5_, aA, aB);                  \
    accum8(M6, v6_, aA, aB); accum8(M7, v7_, aA, aB);                  \
} while (0)

// SpMM: 32 consecutive rows/block (contiguous edge segment), cols/vals
// staged in LDS. SAME-BODY deep pipeline: issue 16 gathers (batches A,B),
// vmcnt(8) -> consume A (B stays in flight under A's VALU), vmcnt(0) ->
// consume B. No asm value crosses an iteration boundary (round 10's NaN:
// loop-carried asm results got PHI-copied before the load completed).
__global__ __launch_bounds__(BLOCK, 2) void spmm_kernel(
    const int*          __restrict__ cols,
    const float*        __restrict__ vals,
    const unsigned int* __restrict__ emb_bf,
    const int*          __restrict__ row_ptr,
    float*              __restrict__ out) {
    __shared__ int   s_cols[LDS_EDGES];
    __shared__ float s_vals[LDS_EDGES];

    const int tid  = threadIdx.x;
    const int base = blockIdx.x * RPB;
    const int rlim = (base + RPB < N_NODES) ? base + RPB : N_NODES;
    const int e0   = row_ptr[base];
    const int n_e  = row_ptr[rlim] - e0;
    const bool fits = (n_e <= LDS_EDGES);

    if (fits) {
        for (int j = tid; j < n_e; j += BLOCK) {
            s_cols[j] = cols[e0 + j];
            s_vals[j] = vals[e0 + j];
        }
    }
    __syncthreads();

    const int lrow = tid / LPR;
    const int fg   = tid - lrow * LPR;
    const int r    = base + lrow;
    if (r >= N_NODES) return;

    const int start = row_ptr[r]     - e0;
    const int lend  = row_ptr[r + 1] - e0;
    const char* embB = (const char*)emb_bf + fg * 16;

    float4 aA = make_float4(0.f, 0.f, 0.f, 0.f);
    float4 aB = aA;
    float4* o = (float4*)out;
    const size_t ob = (size_t)r * 24 + fg * 2;

    if (!fits) {   // safety path (not taken for this distribution)
        for (int e = e0 + start; e < e0 + lend; ++e) {
            int   c = cols[e];
            float v = vals[e];
            u32x4 m = *(const u32x4*)(embB + (size_t)c * ROW_BYTES);
            accum8(m, v, aA, aB);
        }
        o[ob + 0] = aA; o[ob + 1] = aB;
        return;
    }

    if (n_e == 0) {
        o[ob + 0] = aA; o[ob + 1] = aB;
        return;
    }
    const int ncl = n_e - 1;
    const int nB  = (lend - start + EB - 1) / EB;   // 8-edge batches

    u32x4 A0, A1, A2, A3, A4, A5, A6, A7;
    u32x4 B0, B1, B2, B3, B4, B5, B6, B7;

    int i = 0;
    for (; i + 1 < nB; i += 2) {
        ISSUE(i,     A0, A1, A2, A3, A4, A5, A6, A7);
        ISSUE(i + 1, B0, B1, B2, B3, B4, B5, B6, B7);
        PIPE_WAIT(8);          // A complete; B's 8 still in flight
        ACCB(i,     A0, A1, A2, A3, A4, A5, A6, A7);
        PIPE_WAIT(0);          // B complete
        ACCB(i + 1, B0, B1, B2, B3, B4, B5, B6, B7);
    }
    if (i < nB) {
        ISSUE(i, A0, A1, A2, A3, A4, A5, A6, A7);
        PIPE_WAIT(0);
        ACCB(i, A0, A1, A2, A3, A4, A5, A6, A7);
    }

    o[ob + 0] = aA;
    o[ob + 1] = aB;
}

// ---------- fallback f32 path (ws too small; proven round-2/5) ----------
#define F4 (D_FEAT / 4)
__global__ __launch_bounds__(384, 2) void spmm_f32_kernel(
    const int*   __restrict__ cols,
    const float* __restrict__ vals,
    const float* __restrict__ embeds,
    const int*   __restrict__ row_ptr,
    float*       __restrict__ out) {
    const int tid       = threadIdx.x;
    const int local_row = tid / F4;
    const int fg        = tid - local_row * F4;
    const int r         = blockIdx.x * 16 + local_row;
    if (r >= N_NODES) return;
    const float4* __restrict__ emb4 = (const float4*)embeds;
    int e = row_ptr[r], end = row_ptr[r + 1];
    float4 a0 = make_float4(0.f, 0.f, 0.f, 0.f), a1 = a0, a2 = a0, a3 = a0;
    for (; e + 3 < end; e += 4) {
        int c0 = cols[e], c1 = cols[e + 1], c2 = cols[e + 2], c3 = cols[e + 3];
        float v0 = vals[e], v1 = vals[e + 1], v2 = vals[e + 2], v3 = vals[e + 3];
        float4 m0 = emb4[c0 * F4 + fg], m1 = emb4[c1 * F4 + fg];
        float4 m2 = emb4[c2 * F4 + fg], m3 = emb4[c3 * F4 + fg];
        a0.x += v0 * m0.x; a0.y += v0 * m0.y; a0.z += v0 * m0.z; a0.w += v0 * m0.w;
        a1.x += v1 * m1.x; a1.y += v1 * m1.y; a1.z += v1 * m1.z; a1.w += v1 * m1.w;
        a2.x += v2 * m2.x; a2.y += v2 * m2.y; a2.z += v2 * m2.z; a2.w += v2 * m2.w;
        a3.x += v3 * m3.x; a3.y += v3 * m3.y; a3.z += v3 * m3.z; a3.w += v3 * m3.w;
    }
    for (; e < end; ++e) {
        int c = cols[e]; float v = vals[e];
        float4 m = emb4[c * F4 + fg];
        a0.x += v * m.x; a0.y += v * m.y; a0.z += v * m.z; a0.w += v * m.w;
    }
    float4 s;
    s.x = (a0.x + a1.x) + (a2.x + a3.x);
    s.y = (a0.y + a1.y) + (a2.y + a3.y);
    s.z = (a0.z + a1.z) + (a2.z + a3.z);
    s.w = (a0.w + a1.w) + (a2.w + a3.w);
    ((float4*)out)[r * F4 + fg] = s;
}

__global__ void build_row_ptr_kernel(const int* __restrict__ rows,
                                     int* __restrict__ row_ptr) {
    int r = blockIdx.x * blockDim.x + threadIdx.x;
    if (r > N_NODES) return;
    int lo = 0, hi = N_EDGES;
    while (lo < hi) {
        int mid = (lo + hi) >> 1;
        if (rows[mid] < r) lo = mid + 1;
        else hi = mid;
    }
    row_ptr[r] = lo;
}

extern "C" void kernel_launch(void* const* d_in, const int* in_sizes, int n_in,
                              void* d_out, int out_size, void* d_ws, size_t ws_size,
                              hipStream_t stream) {
    const int*   rows   = (const int*)  d_in[0];
    const int*   cols   = (const int*)  d_in[1];
    const float* vals   = (const float*)d_in[2];
    const float* embeds = (const float*)d_in[3];
    float*       out    = (float*)      d_out;

    int* row_ptr = (int*)d_ws;

    if (ws_size >= WS_NEEDED) {
        unsigned int* emb_bf = (unsigned int*)((char*)d_ws + EMB_OFF);
        {
            int threads = 256;
            int blocks  = (N_CVT + threads - 1) / threads;   // 2344
            prep_kernel<<<blocks, threads, 0, stream>>>(rows, embeds, emb_bf,
                                                        row_ptr);
        }
        {
            int blocks = (N_NODES + RPB - 1) / RPB;          // 1563
            spmm_kernel<<<blocks, BLOCK, 0, stream>>>(cols, vals, emb_bf,
                                                      row_ptr, out);
        }
    } else {
        {
            int threads = 256;
            int blocks  = (N_NODES + 1 + threads - 1) / threads;
            build_row_ptr_kernel<<<blocks, threads, 0, stream>>>(rows, row_ptr);
        }
        {
            int blocks = (N_NODES + 15) / 16;
            spmm_f32_kernel<<<blocks, 384, 0, stream>>>(cols, vals, embeds,
                                                        row_ptr, out);
        }
    }
}

// Round 13
// 45.687 us; speedup vs baseline: 2.5369x; 1.0052x over previous
//
#include <hip/hip_runtime.h>

#define N_NODES 50000
#define N_EDGES 800000
#define D_FEAT  96
#define PLANE_FEAT 48                 // features per plane
#define PL_ROW_BYTES 96               // 48 bf16 = 96 B = 6 granules x 16B
#define LPR 6                         // lanes per row (1 granule each, per pass)
#define RPB 32                        // rows per block
#define BLOCK (RPB * LPR)             // 192
#define NBLK ((N_NODES + RPB - 1) / RPB)  // 1563 row-blocks per pass
#define LDS_EDGES 2048                // block edge segment capacity (avg 512)
#define EB 8                          // edges per batch; 2 batches in flight

#define N_CVT  (N_NODES * D_FEAT / 8) // 600000 convert threads (1 granule each)
// d_ws layout: row_ptr | plane_lo | plane_hi
#define PLANE_OFF 200192              // after row_ptr (200004 B), 16B aligned
#define PLANE_BYTES ((size_t)N_NODES * PL_ROW_BYTES)   // 4,800,000
#define WS_NEEDED (PLANE_OFF + 2 * PLANE_BYTES)        // ~9.8 MB

typedef unsigned int u32x4 __attribute__((ext_vector_type(4)));

__device__ __forceinline__ u32x4 gload16(const void* p) {
    u32x4 r;
    asm volatile("global_load_dwordx4 %0, %1, off" : "=v"(r) : "v"(p));
    return r;
}

// wait until <= n vector-memory ops outstanding, then fence the scheduler
// (rule #18: sched_barrier so ALU consumers aren't hoisted above the wait).
#define PIPE_WAIT(n) do {                                              \
    asm volatile("s_waitcnt vmcnt(" #n ")" ::: "memory");              \
    __builtin_amdgcn_sched_barrier(0);                                 \
} while (0)

__device__ __forceinline__ unsigned int f2bf(float f) {  // RNE f32->bf16
    unsigned u = __float_as_uint(f);
    return (u + 0x7fffu + ((u >> 16) & 1u)) >> 16;
}

__device__ __forceinline__ void accum8(u32x4 m, float v, float4& A, float4& B) {
    A.x += v * __uint_as_float(m[0] << 16);
    A.y += v * __uint_as_float(m[0] & 0xffff0000u);
    A.z += v * __uint_as_float(m[1] << 16);
    A.w += v * __uint_as_float(m[1] & 0xffff0000u);
    B.x += v * __uint_as_float(m[2] << 16);
    B.y += v * __uint_as_float(m[2] & 0xffff0000u);
    B.z += v * __uint_as_float(m[3] << 16);
    B.w += v * __uint_as_float(m[3] & 0xffff0000u);
}

// Prep: f32->bf16 convert into TWO feature planes (feats 0-47 / 48-95,
// each 4.8 MB ~= one XCD L2) + row_ptr binary search.
__global__ void prep_kernel(const int* __restrict__ rows,
                            const float* __restrict__ embeds,
                            unsigned int* __restrict__ plane_lo,
                            unsigned int* __restrict__ plane_hi,
                            int* __restrict__ row_ptr) {
    const int idx = blockIdx.x * blockDim.x + threadIdx.x;
    if (idx < N_CVT) {
        const float4* src = (const float4*)embeds;
        float4 a = src[idx * 2 + 0];
        float4 b = src[idx * 2 + 1];
        uint4 p;
        p.x = f2bf(a.x) | (f2bf(a.y) << 16);
        p.y = f2bf(a.z) | (f2bf(a.w) << 16);
        p.z = f2bf(b.x) | (f2bf(b.y) << 16);
        p.w = f2bf(b.z) | (f2bf(b.w) << 16);
        const int node = idx / 12;          // 12 granules per 96-feat row
        const int g    = idx - node * 12;   // 0..11
        uint4* dst = (uint4*)(g < 6 ? plane_lo : plane_hi);
        dst[node * 6 + (g >= 6 ? g - 6 : g)] = p;
    }
    if (idx <= N_NODES) {
        int lo = 0, hi = N_EDGES;
        while (lo < hi) {
            int mid = (lo + hi) >> 1;
            if (rows[mid] < idx) lo = mid + 1;
            else hi = mid;
        }
        row_ptr[idx] = lo;
    }
}

// issue one batch of 8 gathers. s_cols holds PRE-SCALED byte offsets
// (col*96). Indices clamped to staged range; slots past the row's end
// load harmless real data that ACCB multiplies by v=0.
#define ISSUE(i, M0, M1, M2, M3, M4, M5, M6, M7) do {                  \
    int bx_ = start + (i) * EB;                                        \
    int j0_ = bx_ + 0; j0_ = j0_ > ncl ? ncl : j0_;                    \
    int j1_ = bx_ + 1; j1_ = j1_ > ncl ? ncl : j1_;                    \
    int j2_ = bx_ + 2; j2_ = j2_ > ncl ? ncl : j2_;                    \
    int j3_ = bx_ + 3; j3_ = j3_ > ncl ? ncl : j3_;                    \
    int j4_ = bx_ + 4; j4_ = j4_ > ncl ? ncl : j4_;                    \
    int j5_ = bx_ + 5; j5_ = j5_ > ncl ? ncl : j5_;                    \
    int j6_ = bx_ + 6; j6_ = j6_ > ncl ? ncl : j6_;                    \
    int j7_ = bx_ + 7; j7_ = j7_ > ncl ? ncl : j7_;                    \
    M0 = gload16(embB + (size_t)(unsigned)s_cols[j0_]);                \
    M1 = gload16(embB + (size_t)(unsigned)s_cols[j1_]);                \
    M2 = gload16(embB + (size_t)(unsigned)s_cols[j2_]);                \
    M3 = gload16(embB + (size_t)(unsigned)s_cols[j3_]);                \
    M4 = gload16(embB + (size_t)(unsigned)s_cols[j4_]);                \
    M5 = gload16(embB + (size_t)(unsigned)s_cols[j5_]);                \
    M6 = gload16(embB + (size_t)(unsigned)s_cols[j6_]);                \
    M7 = gload16(embB + (size_t)(unsigned)s_cols[j7_]);                \
} while (0)

#define ACCB(i, M0, M1, M2, M3, M4, M5, M6, M7) do {                   \
    int bx_ = start + (i) * EB;                                        \
    int s0_ = bx_ + 0; float v0_ = s_vals[s0_ > ncl ? ncl : s0_];      \
    int s1_ = bx_ + 1; float v1_ = s_vals[s1_ > ncl ? ncl : s1_];      \
    int s2_ = bx_ + 2; float v2_ = s_vals[s2_ > ncl ? ncl : s2_];      \
    int s3_ = bx_ + 3; float v3_ = s_vals[s3_ > ncl ? ncl : s3_];      \
    int s4_ = bx_ + 4; float v4_ = s_vals[s4_ > ncl ? ncl : s4_];      \
    int s5_ = bx_ + 5; float v5_ = s_vals[s5_ > ncl ? ncl : s5_];      \
    int s6_ = bx_ + 6; float v6_ = s_vals[s6_ > ncl ? ncl : s6_];      \
    int s7_ = bx_ + 7; float v7_ = s_vals[s7_ > ncl ? ncl : s7_];      \
    v0_ = (s0_ < lend) ? v0_ : 0.f;  v1_ = (s1_ < lend) ? v1_ : 0.f;   \
    v2_ = (s2_ < lend) ? v2_ : 0.f;  v3_ = (s3_ < lend) ? v3_ : 0.f;   \
    v4_ = (s4_ < lend) ? v4_ : 0.f;  v5_ = (s5_ < lend) ? v5_ : 0.f;   \
    v6_ = (s6_ < lend) ? v6_ : 0.f;  v7_ = (s7_ < lend) ? v7_ : 0.f;   \
    accum8(M0, v0_, aA, aB); accum8(M1, v1_, aA, aB);                  \
    accum8(M2, v2_, aA, aB); accum8(M3, v3_, aA, aB);                  \
    accum8(M4, v4_, aA, aB); accum8(M5, v5_, aA, aB);                  \
    accum8(M6, v6_, aA, aB); accum8(M7, v7_, aA, aB);                  \
} while (0)

// SpMM, two temporally-separated passes over 4.8 MB feature planes.
// blocks [0, NBLK) process plane_lo, [NBLK, 2*NBLK) plane_hi: resident
// blocks at any moment share one ~L2-sized gather footprint.
// Proven depth-2 same-body pipeline (16 asm tuples — round 12 showed
// depth-3's 24 tuples get spilled while in flight -> memory fault).
__global__ __launch_bounds__(BLOCK, 2) void spmm_kernel(
    const int*          __restrict__ cols,
    const float*        __restrict__ vals,
    const unsigned int* __restrict__ plane_lo,
    const unsigned int* __restrict__ plane_hi,
    const int*          __restrict__ row_ptr,
    float*              __restrict__ out) {
    __shared__ int   s_cols[LDS_EDGES];
    __shared__ float s_vals[LDS_EDGES];

    const int bid  = blockIdx.x;
    const int pass = bid >= NBLK ? 1 : 0;
    const int rblk = bid - pass * NBLK;
    const int tid  = threadIdx.x;
    const int base = rblk * RPB;
    const int rlim = (base + RPB < N_NODES) ? base + RPB : N_NODES;
    const int e0   = row_ptr[base];
    const int n_e  = row_ptr[rlim] - e0;
    const bool fits = (n_e <= LDS_EDGES);

    if (fits) {
        for (int j = tid; j < n_e; j += BLOCK) {
            s_cols[j] = cols[e0 + j] * PL_ROW_BYTES;   // pre-scaled byte offset
            s_vals[j] = vals[e0 + j];
        }
    }
    __syncthreads();

    const int lrow = tid / LPR;                 // 0..31
    const int fg   = tid - lrow * LPR;          // 0..5
    const int r    = base + lrow;
    if (r >= N_NODES) return;

    const int start = row_ptr[r]     - e0;
    const int lend  = row_ptr[r + 1] - e0;
    const char* embB =
        (const char*)(pass ? plane_hi : plane_lo) + fg * 16;

    float4 aA = make_float4(0.f, 0.f, 0.f, 0.f);
    float4 aB = aA;
    float4* o = (float4*)out;
    // lane owns feats [pass*48 + fg*8, +8) of row r
    const size_t ob = (size_t)r * 24 + pass * 12 + fg * 2;

    if (!fits) {   // safety path (not taken for this distribution)
        for (int e = e0 + start; e < e0 + lend; ++e) {
            int   c = cols[e];
            float v = vals[e];
            u32x4 m = *(const u32x4*)(embB + (size_t)c * PL_ROW_BYTES);
            accum8(m, v, aA, aB);
        }
        o[ob + 0] = aA; o[ob + 1] = aB;
        return;
    }

    if (n_e == 0) {
        o[ob + 0] = aA; o[ob + 1] = aB;
        return;
    }
    const int ncl = n_e - 1;
    const int nB  = (lend - start + EB - 1) / EB;   // 8-edge batches

    u32x4 A0, A1, A2, A3, A4, A5, A6, A7;
    u32x4 B0, B1, B2, B3, B4, B5, B6, B7;

    int i = 0;
    for (; i + 1 < nB; i += 2) {
        ISSUE(i,     A0, A1, A2, A3, A4, A5, A6, A7);
        ISSUE(i + 1, B0, B1, B2, B3, B4, B5, B6, B7);
        PIPE_WAIT(8);          // A complete; B's 8 still in flight
        ACCB(i,     A0, A1, A2, A3, A4, A5, A6, A7);
        PIPE_WAIT(0);          // B complete
        ACCB(i + 1, B0, B1, B2, B3, B4, B5, B6, B7);
    }
    if (i < nB) {
        ISSUE(i, A0, A1, A2, A3, A4, A5, A6, A7);
        PIPE_WAIT(0);
        ACCB(i, A0, A1, A2, A3, A4, A5, A6, A7);
    }

    o[ob + 0] = aA;
    o[ob + 1] = aB;
}

// ---------- fallback f32 path (ws too small; proven round-2/5) ----------
#define F4 (D_FEAT / 4)
__global__ __launch_bounds__(384, 2) void spmm_f32_kernel(
    const int*   __restrict__ cols,
    const float* __restrict__ vals,
    const float* __restrict__ embeds,
    const int*   __restrict__ row_ptr,
    float*       __restrict__ out) {
    const int tid       = threadIdx.x;
    const int local_row = tid / F4;
    const int fg        = tid - local_row * F4;
    const int r         = blockIdx.x * 16 + local_row;
    if (r >= N_NODES) return;
    const float4* __restrict__ emb4 = (const float4*)embeds;
    int e = row_ptr[r], end = row_ptr[r + 1];
    float4 a0 = make_float4(0.f, 0.f, 0.f, 0.f), a1 = a0, a2 = a0, a3 = a0;
    for (; e + 3 < end; e += 4) {
        int c0 = cols[e], c1 = cols[e + 1], c2 = cols[e + 2], c3 = cols[e + 3];
        float v0 = vals[e], v1 = vals[e + 1], v2 = vals[e + 2], v3 = vals[e + 3];
        float4 m0 = emb4[c0 * F4 + fg], m1 = emb4[c1 * F4 + fg];
        float4 m2 = emb4[c2 * F4 + fg], m3 = emb4[c3 * F4 + fg];
        a0.x += v0 * m0.x; a0.y += v0 * m0.y; a0.z += v0 * m0.z; a0.w += v0 * m0.w;
        a1.x += v1 * m1.x; a1.y += v1 * m1.y; a1.z += v1 * m1.z; a1.w += v1 * m1.w;
        a2.x += v2 * m2.x; a2.y += v2 * m2.y; a2.z += v2 * m2.z; a2.w += v2 * m2.w;
        a3.x += v3 * m3.x; a3.y += v3 * m3.y; a3.z += v3 * m3.z; a3.w += v3 * m3.w;
    }
    for (; e < end; ++e) {
        int c = cols[e]; float v = vals[e];
        float4 m = emb4[c * F4 + fg];
        a0.x += v * m.x; a0.y += v * m.y; a0.z += v * m.z; a0.w += v * m.w;
    }
    float4 s;
    s.x = (a0.x + a1.x) + (a2.x + a3.x);
    s.y = (a0.y + a1.y) + (a2.y + a3.y);
    s.z = (a0.z + a1.z) + (a2.z + a3.z);
    s.w = (a0.w + a1.w) + (a2.w + a3.w);
    ((float4*)out)[r * F4 + fg] = s;
}

__global__ void build_row_ptr_kernel(const int* __restrict__ rows,
                                     int* __restrict__ row_ptr) {
    int r = blockIdx.x * blockDim.x + threadIdx.x;
    if (r > N_NODES) return;
    int lo = 0, hi = N_EDGES;
    while (lo < hi) {
        int mid = (lo + hi) >> 1;
        if (rows[mid] < r) lo = mid + 1;
        else hi = mid;
    }
    row_ptr[r] = lo;
}

extern "C" void kernel_launch(void* const* d_in, const int* in_sizes, int n_in,
                              void* d_out, int out_size, void* d_ws, size_t ws_size,
                              hipStream_t stream) {
    const int*   rows   = (const int*)  d_in[0];
    const int*   cols   = (const int*)  d_in[1];
    const float* vals   = (const float*)d_in[2];
    const float* embeds = (const float*)d_in[3];
    float*       out    = (float*)      d_out;

    int* row_ptr = (int*)d_ws;

    if (ws_size >= WS_NEEDED) {
        unsigned int* plane_lo = (unsigned int*)((char*)d_ws + PLANE_OFF);
        unsigned int* plane_hi = (unsigned int*)((char*)d_ws + PLANE_OFF + PLANE_BYTES);
        {
            int threads = 256;
            int blocks  = (N_CVT + threads - 1) / threads;   // 2344
            prep_kernel<<<blocks, threads, 0, stream>>>(rows, embeds, plane_lo,
                                                        plane_hi, row_ptr);
        }
        {
            int blocks = 2 * NBLK;                           // 3126
            spmm_kernel<<<blocks, BLOCK, 0, stream>>>(cols, vals, plane_lo,
                                                      plane_hi, row_ptr, out);
        }
    } else {
        {
            int threads = 256;
            int blocks  = (N_NODES + 1 + threads - 1) / threads;
            build_row_ptr_kernel<<<blocks, threads, 0, stream>>>(rows, row_ptr);
        }
        {
            int blocks = (N_NODES + 15) / 16;
            spmm_f32_kernel<<<blocks, 384, 0, stream>>>(cols, vals, embeds,
                                                        row_ptr, out);
        }
    }
}